// Round 3
// baseline (6962.217 us; speedup 1.0000x reference)
//
#include <hip/hip_runtime.h>

#define N      4096
#define NBLK   256
#define NTHR   1024
#define RPB    16           // rows per block  (N / NBLK)
#define R      4            // rows per wave
#define NCK    4            // j-chunks per row (waves sharing a row-group)
#define CHUNK  (N / NCK)    // 1024 columns per chunk
#define TPL    (CHUNK / 64) // 16 elements per lane per row

#define LOG2E 1.4426950408889634f

// All scratch lives in static device memory (NOT d_ws: ws_size was never
// validated and an undersized d_ws => OOB writes => GPU fault, the likely
// cause of rounds 0-2 container deaths). ~164 KB, fine as a module global.
struct WS {
  float4 xpack[N];   // x0,x1,x2, |x|^2
  float4 ypack[N];   // y0,y1,y2, |y|^2
  float  fs[N];      // (f/eps + log_u) * log2e  (transformed potential, rows=x)
  float  gs[N];      // (g/eps + log_u) * log2e  (transformed potential, rows=y)
  double accC;       // sum of all pairwise distances (for eps)
  double accE;       // final EMD accumulator
  float  nie2;       // -log2(e)/eps, computed on device
};
__device__ WS g_ws;

__device__ __forceinline__ float ex2f(float v) { return __builtin_amdgcn_exp2f(v); }

// ---------------------------------------------------------------------------
// setup: pack points as (p, |p|^2), init transformed g (g=0 -> -12), zero accums.
// Rewrites every field later passes read, so each call is state-independent.
__global__ void k_setup(const float* __restrict__ x, const float* __restrict__ y)
{
  int i = blockIdx.x * blockDim.x + threadIdx.x;
  if (i < N) {
    float a0 = x[i * 3 + 0], a1 = x[i * 3 + 1], a2 = x[i * 3 + 2];
    g_ws.xpack[i] = make_float4(a0, a1, a2, fmaf(a0, a0, fmaf(a1, a1, a2 * a2)));
    float b0 = y[i * 3 + 0], b1 = y[i * 3 + 1], b2 = y[i * 3 + 2];
    g_ws.ypack[i] = make_float4(b0, b1, b2, fmaf(b0, b0, fmaf(b1, b1, b2 * b2)));
    g_ws.gs[i] = -12.0f;
  }
  if (i == 0) { g_ws.accC = 0.0; g_ws.accE = 0.0; }
}

// ---------------------------------------------------------------------------
// pair-sum pass over all 4096x4096 pairs.
//   emd==0 : accC += sum C_ij                      (for eps)
//   emd==1 : accE += sum 2^(fs_i+gs_j+nie2*C)*C    (final transport cost)
__global__ void __launch_bounds__(NTHR)
k_pair(int emd)
{
  __shared__ double ldsd[16];
  const int tid  = threadIdx.x;
  const int lane = tid & 63;
  const int wid  = tid >> 6;
  const int rg   = wid >> 2;
  const int ck   = wid & 3;
  const int r0   = blockIdx.x * RPB + rg * R;
  const float nie2 = emd ? g_ws.nie2 : 0.f;

  float c0[R], c1[R], c2[R], ca[R], fr[R];
  double acc[R];
#pragma unroll
  for (int r = 0; r < R; ++r) {
    float4 p = g_ws.xpack[r0 + r];
    c0[r] = -2.f * p.x; c1[r] = -2.f * p.y; c2[r] = -2.f * p.z; ca[r] = p.w;
    fr[r] = emd ? g_ws.fs[r0 + r] : 0.f;
    acc[r] = 0.0;
  }

  int j = ck * CHUNK + lane;
  for (int t = 0; t < TPL; ++t, j += 64) {
    float4 q = g_ws.ypack[j];
    float  pj = emd ? g_ws.gs[j] : 0.f;
    float  b  = q.w;
#pragma unroll
    for (int r = 0; r < R; ++r) {
      float d2 = fmaf(c0[r], q.x, fmaf(c1[r], q.y, fmaf(c2[r], q.z, ca[r] + b)));
      d2 = fmaxf(d2, 0.f) + 1e-12f;
      float c = __builtin_amdgcn_sqrtf(d2);
      float term = emd ? ex2f(fmaf(nie2, c, fr[r] + pj)) * c : c;
      acc[r] += (double)term;
    }
  }

  double a = (acc[0] + acc[1]) + (acc[2] + acc[3]);
#pragma unroll
  for (int off = 32; off; off >>= 1) a += __shfl_xor(a, off);
  if (lane == 0) ldsd[wid] = a;
  __syncthreads();
  if (tid == 0) {
    double s = 0.0;
#pragma unroll
    for (int w = 0; w < 16; ++w) s += ldsd[w];
    atomicAdd(emd ? &g_ws.accE : &g_ws.accC, s);
  }
}

// ---------------------------------------------------------------------------
// eps finalize: nie2 = -log2e / (0.02 * mean(C))
__global__ void k_eps()
{
  if (threadIdx.x == 0) {
    float eps = (float)(0.02 * g_ws.accC / ((double)N * (double)N));
    g_ws.nie2 = -LOG2E / eps;
  }
}

// ---------------------------------------------------------------------------
// one logsumexp half-pass: for each row i owned by this block,
//   potOut[i] = -12 - log2( sum_j 2^( potIn[j] + nie2 * C_ij ) )
// dir==0: rows=x, cols=y, reads gs, writes fs.  dir==1: swapped.
__global__ void __launch_bounds__(NTHR)
k_lse(int dir)
{
  __shared__ float part[RPB * NCK * 2];
  const float4* __restrict__ rowPack = dir ? g_ws.ypack : g_ws.xpack;
  const float4* __restrict__ colPack = dir ? g_ws.xpack : g_ws.ypack;
  const float*  __restrict__ potIn   = dir ? g_ws.fs : g_ws.gs;
  float*        __restrict__ potOut  = dir ? g_ws.gs : g_ws.fs;

  const int tid  = threadIdx.x;
  const int lane = tid & 63;
  const int wid  = tid >> 6;   // 0..15
  const int rg   = wid >> 2;   // row-group 0..3
  const int ck   = wid & 3;    // chunk 0..3
  const int rowBase = blockIdx.x * RPB;
  const int r0   = rowBase + rg * R;
  const float nie2 = g_ws.nie2;

  float c0[R], c1[R], c2[R], ca[R], m[R], l[R];
#pragma unroll
  for (int r = 0; r < R; ++r) {
    float4 p = rowPack[r0 + r];
    c0[r] = -2.f * p.x; c1[r] = -2.f * p.y; c2[r] = -2.f * p.z; ca[r] = p.w;
    m[r] = -INFINITY;  l[r] = 0.f;
  }

  int j = ck * CHUNK + lane;
#pragma unroll 4
  for (int t = 0; t < TPL; ++t, j += 64) {
    float4 q = colPack[j];
    float  pj = potIn[j];
    float  b  = q.w;
#pragma unroll
    for (int r = 0; r < R; ++r) {
      float d2 = fmaf(c0[r], q.x, fmaf(c1[r], q.y, fmaf(c2[r], q.z, ca[r] + b)));
      d2 = fmaxf(d2, 0.f) + 1e-12f;
      float c  = __builtin_amdgcn_sqrtf(d2);          // C_ij
      float s  = fmaf(nie2, c, pj);                   // base-2 exponent
      float nm = fmaxf(m[r], s);                      // online LSE (branchless)
      l[r] = fmaf(l[r], ex2f(m[r] - nm), ex2f(s - nm));
      m[r] = nm;
    }
  }

  // wave-level butterfly merge of (m,l)
#pragma unroll
  for (int r = 0; r < R; ++r) {
#pragma unroll
    for (int off = 32; off; off >>= 1) {
      float om = __shfl_xor(m[r], off);
      float ol = __shfl_xor(l[r], off);
      float nm = fmaxf(m[r], om);
      l[r] = fmaf(l[r], ex2f(m[r] - nm), ol * ex2f(om - nm));
      m[r] = nm;
    }
  }

  if (lane == 0) {
#pragma unroll
    for (int r = 0; r < R; ++r) {
      int row = rg * R + r;                  // 0..15 within block
      part[(row * NCK + ck) * 2 + 0] = m[r];
      part[(row * NCK + ck) * 2 + 1] = l[r];
    }
  }
  __syncthreads();

  if (tid < RPB) {   // one thread per row: merge 4 chunk partials, write potential
    float mm = -INFINITY, ll = 0.f;
#pragma unroll
    for (int c = 0; c < NCK; ++c) {
      float om = part[(tid * NCK + c) * 2 + 0];
      float ol = part[(tid * NCK + c) * 2 + 1];
      float nm = fmaxf(mm, om);
      ll = fmaf(ll, ex2f(mm - nm), ol * ex2f(om - nm));
      mm = nm;
    }
    // fs = (f/eps + log_u)*log2e = -12 - (m + log2(l))   [v_log_f32 is log2]
    potOut[rowBase + tid] = -12.0f - (mm + __builtin_amdgcn_logf(ll));
  }
}

// ---------------------------------------------------------------------------
__global__ void k_out(float* __restrict__ out)
{
  if (threadIdx.x == 0) out[0] = (float)g_ws.accE;
}

extern "C" void kernel_launch(void* const* d_in, const int* in_sizes, int n_in,
                              void* d_out, int out_size, void* d_ws, size_t ws_size,
                              hipStream_t stream) {
  const float* x = (const float*)d_in[0];
  const float* y = (const float*)d_in[1];
  float* out = (float*)d_out;
  (void)d_ws; (void)ws_size;

  k_setup<<<dim3((N + 255) / 256), dim3(256), 0, stream>>>(x, y);
  k_pair<<<dim3(NBLK), dim3(NTHR), 0, stream>>>(0);
  k_eps<<<dim3(1), dim3(64), 0, stream>>>();

  for (int it = 0; it < 300; ++it) {
    k_lse<<<dim3(NBLK), dim3(NTHR), 0, stream>>>(0);  // f-update
    k_lse<<<dim3(NBLK), dim3(NTHR), 0, stream>>>(1);  // g-update
  }

  k_pair<<<dim3(NBLK), dim3(NTHR), 0, stream>>>(1);
  k_out<<<dim3(1), dim3(64), 0, stream>>>(out);
}